// Round 1
// baseline (198.742 us; speedup 1.0000x reference)
//
#include <hip/hip_runtime.h>
#include <cstdint>
#include <cstddef>

typedef __attribute__((ext_vector_type(8))) short short8;
typedef __attribute__((ext_vector_type(4))) float floatx4;

typedef __attribute__((address_space(1))) const void gvoid_t;
typedef __attribute__((address_space(3))) void lvoid_t;

// fp32 -> bf16 with round-to-nearest-even (bit pattern as short)
__device__ inline short f2bf(float f) {
    unsigned u = __float_as_uint(f);
    u = (u + 0x7FFFu + ((u >> 16) & 1u)) >> 16;
    return (short)u;
}

// ---------------------------------------------------------------------------
// Merged prologue (unchanged, measured ~15us ~= 88MB/6.3TBps roofline):
// blocks [0,ncvt) convert x fp32->bf16; blocks [ncvt,..) dequantize qweight
// into transposed bf16 deqT [N][K].
// ---------------------------------------------------------------------------
__global__ __launch_bounds__(256) void prologue_kernel(
    const float* __restrict__ x, short* __restrict__ xb, long long nx, int ncvt,
    const int* __restrict__ qw, const float* __restrict__ scales,
    const float* __restrict__ zps, short* __restrict__ deqT,
    int N, int K, int nbx)
{
    __shared__ int lds_q[32 * 65];
    const int t = threadIdx.x;

    if ((int)blockIdx.x < ncvt) {
        // ---- convert x ----
        long long i = ((long long)blockIdx.x * 256 + t) * 8;
        if (i + 8 > nx) return;
        const float4* p = (const float4*)(x + i);
        float4 v0 = p[0];
        float4 v1 = p[1];
        short8 h;
        h[0] = f2bf(v0.x); h[1] = f2bf(v0.y); h[2] = f2bf(v0.z); h[3] = f2bf(v0.w);
        h[4] = f2bf(v1.x); h[5] = f2bf(v1.y); h[6] = f2bf(v1.z); h[7] = f2bf(v1.w);
        *(short8*)(xb + i) = h;
        return;
    }

    // ---- dequant ----
    const int b2 = (int)blockIdx.x - ncvt;
    const int n0 = (b2 % nbx) * 64;
    const int r0 = (b2 / nbx) * 32;   // qweight row tile (32 rows = 256 k)

    #pragma unroll
    for (int v = 0; v < 2; ++v) {
        int idx = t + v * 256;            // 0..511 int4-chunks
        int row = idx >> 4;               // 16 int4 per 64-col row
        int c4  = (idx & 15) * 4;
        const int4 q4 = *(const int4*)(qw + (size_t)(r0 + row) * N + n0 + c4);
        int base = row * 65 + c4;
        lds_q[base + 0] = q4.x;
        lds_q[base + 1] = q4.y;
        lds_q[base + 2] = q4.z;
        lds_q[base + 3] = q4.w;
    }
    __syncthreads();

    const int L  = t & 63;
    const int w  = t >> 6;
    const int rq = L & 31;            // qw row this lane unpacks
    const int hi = L >> 5;            // 0: row 2p, 1: row 2p+1
    const int g  = (r0 + rq) >> 4;    // quant group of this lane's 8 k-values

    #pragma unroll
    for (int it = 0; it < 8; ++it) {
        const int p  = w * 8 + it;    // row-pair index 0..31
        const int nl = 2 * p + hi;    // local n row 0..63

        float s = scales[(size_t)g * N + n0 + nl];
        s = fminf(fmaxf(s, 1e-5f), 1e4f);
        float z = rintf(zps[(size_t)g * N + n0 + nl]);
        z = fminf(fmaxf(z, 0.0f), 15.0f);

        const int q = lds_q[rq * 65 + nl];
        short8 h;
        #pragma unroll
        for (int j = 0; j < 8; ++j) {
            float f = (float)((q >> (4 * j)) & 15);
            h[j] = f2bf((f - z) * s);
        }
        *(short8*)(deqT + (size_t)(n0 + nl) * K + (size_t)(r0 + rq) * 8) = h;
    }
}

// ---------------------------------------------------------------------------
// Kernel 2: bf16 GEMM, C = A[M][K] * Bt[N][K]^T + bias, fp32 out.
//
// R9: port of the learn_hip 8-phase counted-vmcnt schedule (T3+T4+T5) adapted
// to M=2048: BM=128 x BN=256 (grid 16x16 = 256 blocks fills all 256 CUs; a
// straight 256^2 tile would give only 128 blocks = half machine), BK=64,
// 512 threads = 8 waves (2m x 4n), per-wave 64x64 output. 96KB LDS (2 x
// (16KB A + 32KB B)), 1 block/CU.
//
// Per K-tile: 4 phases, each {ds_read frag subtile; lgkmcnt(0)+sched_barrier;
// s_barrier; setprio(1); 8 MFMA; setprio(0); s_barrier}. Frag reads are
// partitioned {6,2,6,2} with register reuse (16 ds_read_b128 total -- no
// re-reads; re-reading would push LDS traffic past the 128B/clk/CU budget).
//
// Counted vmcnt (never 0 in steady state): tile t+2's 6 global_load_lds are
// issued in iter t's P4 *after* P4's open barrier -- at that point every
// wave's lgkmcnt(0) for ALL reads of buf[cur] has executed before a barrier,
// so the overwrite is race-free by ordering (not timing). At the P4 wait
// point outstanding = t+1's 6 + t+2's 6 = 12 -> s_waitcnt vmcnt(6) retires
// exactly tile t+1 (consumed next iter). Loads live across ~7 phases
// (~2000cy >> 900cy HBM latency). Tail: vmcnt(0) only at t=NT-2.
//
// LDS swizzle: same XOR-chunk scheme as R5 (measured 0 bank conflicts):
// staging lane (sr=L>>3, sc=L&7) fetches global chunk gc=sc^sr, so
// LDS[row][pos] holds global chunk pos^(row&7); reads use p=c^(L&7).
// ---------------------------------------------------------------------------
#define BM 128
#define BN 256
#define BK 64

#define LGKM0_FENCE() do { \
    asm volatile("s_waitcnt lgkmcnt(0)" ::: "memory"); \
    __builtin_amdgcn_sched_barrier(0); \
} while (0)

__global__ __launch_bounds__(512, 2) void gemm_bf16_bt(
    const short* __restrict__ A, const short* __restrict__ Bt,
    const float* __restrict__ bias, float* __restrict__ C,
    int M, int N, int K)
{
    __shared__ __align__(16) short a_lds[2][BM * BK];   // 2 x 16 KB
    __shared__ __align__(16) short b_lds[2][BN * BK];   // 2 x 32 KB

    const int t = threadIdx.x;
    const int L = t & 63;
    const int w = t >> 6;            // 0..7

    // XCD swizzle (bijective: nwg = 256, nbn = 16 divisible by 8): XCD k owns
    // n-tiles [2k, 2k+2) x all m-tiles -> 4MB B strip resident per XCD L2,
    // A streams with in-XCD reuse. Performance-only (G16-safe).
    const int nbn = N / BN;
    const int id  = blockIdx.x;
    int nt, mt;
    if ((nbn & 7) == 0) {
        const int xcd = id & 7;
        const int loc = id >> 3;
        const int gsz = nbn >> 3;
        nt = xcd * gsz + (loc % gsz);
        mt = loc / gsz;
    } else {
        nt = id % nbn;
        mt = id / nbn;
    }
    const int m0 = mt * BM;
    const int n0 = nt * BN;

    const int wm = (w & 1) * 64;
    const int wn = (w >> 1) * 64;

    floatx4 acc[4][4] = {};

    // staging geometry: one global_load_lds per wave covers 1KB = 8 rows of
    // 128B; A needs 2 per wave (128 rows), B needs 4 (256 rows).
    const int sr = L >> 3;
    const int sc = L & 7;
    const int gc = sc ^ sr;
    const short* ag = A  + (size_t)(m0 + w * 8 + sr) * K + gc * 8;
    const short* bg = Bt + (size_t)(n0 + w * 8 + sr) * K + gc * 8;
    const int adst = (w * 8) * BK;    // wave-uniform LDS offset (shorts)

    const int NT = K / BK;

    const int l15 = L & 15, l4 = L >> 4, l7 = L & 7;
    const int p0 = l4 ^ l7;          // kstep 0 chunk position
    const int p1 = (4 + l4) ^ l7;    // kstep 1 chunk position

#define STAGE(kt_, buf_) do { \
    const size_t ko_ = (size_t)(kt_) * BK; \
    __builtin_amdgcn_global_load_lds((gvoid_t*)(ag + ko_), \
        (lvoid_t*)(&a_lds[buf_][adst]), 16, 0, 0); \
    __builtin_amdgcn_global_load_lds((gvoid_t*)(ag + (size_t)64 * K + ko_), \
        (lvoid_t*)(&a_lds[buf_][adst + 64 * BK]), 16, 0, 0); \
    __builtin_amdgcn_global_load_lds((gvoid_t*)(bg + ko_), \
        (lvoid_t*)(&b_lds[buf_][adst]), 16, 0, 0); \
    __builtin_amdgcn_global_load_lds((gvoid_t*)(bg + (size_t)64 * K + ko_), \
        (lvoid_t*)(&b_lds[buf_][adst + 64 * BK]), 16, 0, 0); \
    __builtin_amdgcn_global_load_lds((gvoid_t*)(bg + (size_t)128 * K + ko_), \
        (lvoid_t*)(&b_lds[buf_][adst + 128 * BK]), 16, 0, 0); \
    __builtin_amdgcn_global_load_lds((gvoid_t*)(bg + (size_t)192 * K + ko_), \
        (lvoid_t*)(&b_lds[buf_][adst + 192 * BK]), 16, 0, 0); \
} while (0)

    // prologue: tiles 0 and 1 in flight (12 loads); vmcnt(6) -> tile 0 done.
    STAGE(0, 0);
    STAGE(1, 1);
    asm volatile("s_waitcnt vmcnt(6)" ::: "memory");
    __builtin_amdgcn_s_barrier();

    for (int ti = 0; ti < NT; ++ti) {
        const int cur = ti & 1;
        short8 a0[4], a1[4], b0f[4], b1f[4];

        // ---- P1: read A kstep0 (4) + B n0,n1 kstep0 (2); MFMA s0 x n{0,1}
        #pragma unroll
        for (int i = 0; i < 4; ++i)
            a0[i] = *(const short8*)(&a_lds[cur][(wm + 16 * i + l15) * BK + p0 * 8]);
        #pragma unroll
        for (int j = 0; j < 2; ++j)
            b0f[j] = *(const short8*)(&b_lds[cur][(wn + 16 * j + l15) * BK + p0 * 8]);
        LGKM0_FENCE();
        __builtin_amdgcn_s_barrier();
        __builtin_amdgcn_s_setprio(1);
        #pragma unroll
        for (int i = 0; i < 4; ++i) {
            acc[i][0] = __builtin_amdgcn_mfma_f32_16x16x32_bf16(a0[i], b0f[0], acc[i][0], 0, 0, 0);
            acc[i][1] = __builtin_amdgcn_mfma_f32_16x16x32_bf16(a0[i], b0f[1], acc[i][1], 0, 0, 0);
        }
        __builtin_amdgcn_s_setprio(0);
        __builtin_amdgcn_s_barrier();

        // ---- P2: read B n2,n3 kstep0 (2); MFMA s0 x n{2,3} (A regs reused)
        #pragma unroll
        for (int j = 2; j < 4; ++j)
            b0f[j] = *(const short8*)(&b_lds[cur][(wn + 16 * j + l15) * BK + p0 * 8]);
        LGKM0_FENCE();
        __builtin_amdgcn_s_barrier();
        __builtin_amdgcn_s_setprio(1);
        #pragma unroll
        for (int i = 0; i < 4; ++i) {
            acc[i][2] = __builtin_amdgcn_mfma_f32_16x16x32_bf16(a0[i], b0f[2], acc[i][2], 0, 0, 0);
            acc[i][3] = __builtin_amdgcn_mfma_f32_16x16x32_bf16(a0[i], b0f[3], acc[i][3], 0, 0, 0);
        }
        __builtin_amdgcn_s_setprio(0);
        __builtin_amdgcn_s_barrier();

        // ---- P3: read A kstep1 (4) + B n0,n1 kstep1 (2); MFMA s1 x n{0,1}
        #pragma unroll
        for (int i = 0; i < 4; ++i)
            a1[i] = *(const short8*)(&a_lds[cur][(wm + 16 * i + l15) * BK + p1 * 8]);
        #pragma unroll
        for (int j = 0; j < 2; ++j)
            b1f[j] = *(const short8*)(&b_lds[cur][(wn + 16 * j + l15) * BK + p1 * 8]);
        LGKM0_FENCE();
        __builtin_amdgcn_s_barrier();
        __builtin_amdgcn_s_setprio(1);
        #pragma unroll
        for (int i = 0; i < 4; ++i) {
            acc[i][0] = __builtin_amdgcn_mfma_f32_16x16x32_bf16(a1[i], b1f[0], acc[i][0], 0, 0, 0);
            acc[i][1] = __builtin_amdgcn_mfma_f32_16x16x32_bf16(a1[i], b1f[1], acc[i][1], 0, 0, 0);
        }
        __builtin_amdgcn_s_setprio(0);
        __builtin_amdgcn_s_barrier();

        // ---- P4: read B n2,n3 kstep1 (2); stage tile ti+2 into buf cur
        //      (safe: every wave's lgkmcnt(0) for ALL reads of cur precedes
        //      this phase's open barrier); MFMA s1 x n{2,3}; counted vmcnt.
        #pragma unroll
        for (int j = 2; j < 4; ++j)
            b1f[j] = *(const short8*)(&b_lds[cur][(wn + 16 * j + l15) * BK + p1 * 8]);
        LGKM0_FENCE();
        __builtin_amdgcn_s_barrier();
        if (ti + 2 < NT) {
            STAGE(ti + 2, cur);
        }
        __builtin_amdgcn_s_setprio(1);
        #pragma unroll
        for (int i = 0; i < 4; ++i) {
            acc[i][2] = __builtin_amdgcn_mfma_f32_16x16x32_bf16(a1[i], b1f[2], acc[i][2], 0, 0, 0);
            acc[i][3] = __builtin_amdgcn_mfma_f32_16x16x32_bf16(a1[i], b1f[3], acc[i][3], 0, 0, 0);
        }
        __builtin_amdgcn_s_setprio(0);
        if (ti + 2 < NT) {
            // outstanding = tile ti+1 (6) + tile ti+2 (6); retire ti+1's.
            asm volatile("s_waitcnt vmcnt(6)" ::: "memory");
        } else if (ti + 1 < NT) {
            // tail: nothing newer than tile ti+1 -> full drain once.
            asm volatile("s_waitcnt vmcnt(0)" ::: "memory");
        }
        __builtin_amdgcn_s_barrier();
    }

    // Epilogue: C/D layout col = lane&15, row = (lane>>4)*4 + reg  (m89/m91)
    float bv[4];
    #pragma unroll
    for (int j = 0; j < 4; ++j)
        bv[j] = bias[n0 + wn + 16 * j + l15];
    const int col0 = n0 + wn + l15;
    #pragma unroll
    for (int i = 0; i < 4; ++i) {
        const int row0 = m0 + wm + 16 * i + l4 * 4;
        #pragma unroll
        for (int r = 0; r < 4; ++r) {
            float* outr = C + (size_t)(row0 + r) * N + col0;
            #pragma unroll
            for (int j = 0; j < 4; ++j)
                outr[16 * j] = acc[i][j][r] + bv[j];
        }
    }
}

// ---------------------------------------------------------------------------
extern "C" void kernel_launch(void* const* d_in, const int* in_sizes, int n_in,
                              void* d_out, int out_size, void* d_ws, size_t ws_size,
                              hipStream_t stream)
{
    const float* x      = (const float*)d_in[0];
    const float* scales = (const float*)d_in[1];
    const float* zps    = (const float*)d_in[2];
    const float* bias   = (const float*)d_in[3];
    const int*   qw     = (const int*)d_in[4];

    const int N = in_sizes[3];          // outfeatures (bias length)
    const int G = in_sizes[1] / N;      // num groups
    const int K = G * 128;              // infeatures
    const int M = in_sizes[0] / K;      // tokens

    short* xb   = (short*)d_ws;                       // M*K bf16
    short* deqT = xb + (size_t)M * K;                 // N*K bf16
    float* out  = (float*)d_out;

    const long long nx = (long long)M * K;
    const int ncvt = (int)(nx / 2048);
    const int nbx  = N / 64;
    const int ndq  = nbx * (K / 256);

    prologue_kernel<<<ncvt + ndq, 256, 0, stream>>>(
        x, xb, nx, ncvt, qw, scales, zps, deqT, N, K, nbx);
    gemm_bf16_bt<<<dim3((M / BM) * (N / BN)), 512, 0, stream>>>(
        xb, deqT, bias, out, M, N, K);
}

// Round 2
// 180.197 us; speedup vs baseline: 1.1029x; 1.1029x over previous
//
#include <hip/hip_runtime.h>
#include <cstdint>
#include <cstddef>

typedef __attribute__((ext_vector_type(8))) short short8;
typedef __attribute__((ext_vector_type(4))) float floatx4;

typedef __attribute__((address_space(1))) const void gvoid_t;
typedef __attribute__((address_space(3))) void lvoid_t;

// fp32 -> bf16 with round-to-nearest-even (bit pattern as short)
__device__ inline short f2bf(float f) {
    unsigned u = __float_as_uint(f);
    u = (u + 0x7FFFu + ((u >> 16) & 1u)) >> 16;
    return (short)u;
}

// ---------------------------------------------------------------------------
// Merged prologue (unchanged, measured ~15us ~= 88MB/6.3TBps roofline):
// blocks [0,ncvt) convert x fp32->bf16; blocks [ncvt,..) dequantize qweight
// into transposed bf16 deqT [N][K].
// ---------------------------------------------------------------------------
__global__ __launch_bounds__(256) void prologue_kernel(
    const float* __restrict__ x, short* __restrict__ xb, long long nx, int ncvt,
    const int* __restrict__ qw, const float* __restrict__ scales,
    const float* __restrict__ zps, short* __restrict__ deqT,
    int N, int K, int nbx)
{
    __shared__ int lds_q[32 * 65];
    const int t = threadIdx.x;

    if ((int)blockIdx.x < ncvt) {
        // ---- convert x ----
        long long i = ((long long)blockIdx.x * 256 + t) * 8;
        if (i + 8 > nx) return;
        const float4* p = (const float4*)(x + i);
        float4 v0 = p[0];
        float4 v1 = p[1];
        short8 h;
        h[0] = f2bf(v0.x); h[1] = f2bf(v0.y); h[2] = f2bf(v0.z); h[3] = f2bf(v0.w);
        h[4] = f2bf(v1.x); h[5] = f2bf(v1.y); h[6] = f2bf(v1.z); h[7] = f2bf(v1.w);
        *(short8*)(xb + i) = h;
        return;
    }

    // ---- dequant ----
    const int b2 = (int)blockIdx.x - ncvt;
    const int n0 = (b2 % nbx) * 64;
    const int r0 = (b2 / nbx) * 32;   // qweight row tile (32 rows = 256 k)

    #pragma unroll
    for (int v = 0; v < 2; ++v) {
        int idx = t + v * 256;            // 0..511 int4-chunks
        int row = idx >> 4;               // 16 int4 per 64-col row
        int c4  = (idx & 15) * 4;
        const int4 q4 = *(const int4*)(qw + (size_t)(r0 + row) * N + n0 + c4);
        int base = row * 65 + c4;
        lds_q[base + 0] = q4.x;
        lds_q[base + 1] = q4.y;
        lds_q[base + 2] = q4.z;
        lds_q[base + 3] = q4.w;
    }
    __syncthreads();

    const int L  = t & 63;
    const int w  = t >> 6;
    const int rq = L & 31;            // qw row this lane unpacks
    const int hi = L >> 5;            // 0: row 2p, 1: row 2p+1
    const int g  = (r0 + rq) >> 4;    // quant group of this lane's 8 k-values

    #pragma unroll
    for (int it = 0; it < 8; ++it) {
        const int p  = w * 8 + it;    // row-pair index 0..31
        const int nl = 2 * p + hi;    // local n row 0..63

        float s = scales[(size_t)g * N + n0 + nl];
        s = fminf(fmaxf(s, 1e-5f), 1e4f);
        float z = rintf(zps[(size_t)g * N + n0 + nl]);
        z = fminf(fmaxf(z, 0.0f), 15.0f);

        const int q = lds_q[rq * 65 + nl];
        short8 h;
        #pragma unroll
        for (int j = 0; j < 8; ++j) {
            float f = (float)((q >> (4 * j)) & 15);
            h[j] = f2bf((f - z) * s);
        }
        *(short8*)(deqT + (size_t)(n0 + nl) * K + (size_t)(r0 + rq) * 8) = h;
    }
}

// ---------------------------------------------------------------------------
// Kernel 2: bf16 GEMM, C = A[M][K] * Bt[N][K]^T + bias, fp32 out.
//
// R10: fix of R9's two deviations from the proven m201 schedule:
//   (1) lgkmcnt(0) now AFTER each phase's open barrier (R9 fenced before the
//       barrier -> LDS drain / barrier / MFMA fully serialized per phase;
//       MfmaUtil dropped 37->25%). Reads are in flight across the barrier
//       sync; setprio wave-stagger overlaps LDS service with MFMA backlog.
//   (2) 16-MFMA phases (2 per K-tile, 4 barriers/tile) instead of 8-MFMA
//       phases (8 barriers + 4 exposed drains/tile).
// The WAR hazard that forced R9's early fence is solved structurally:
// TRIPLE-buffered K-tiles (144KB LDS, 1 block/CU). STAGE(ti+2) targets the
// slot last read at tile ti-1; those reads completed (lgkmcnt(0)) before
// tile ti-1's close barrier, and STAGE issues after it -> race-free by
// ordering with all waits after the open barrier.
// Counted vmcnt, never 0 in steady state: at tile ti's P2 wait point the
// outstanding loads are tile ti+1 (6) + tile ti+2 (6) -> vmcnt(6) retires
// exactly tile ti+1. Tail: vmcnt(0) only at ti = NT-2.
//
// Geometry: BM=128 x BN=256, BK=64, 512 threads = 8 waves (2m x 4n), 64x64
// per wave; grid 16x16 = 256 blocks = 1 per CU. LDS-read budget per tile:
// 16 ds_read_b128/wave (each fragment read once) -> ceiling ~1680 TF, not
// binding at the ~1200-1400 TF target.
//
// LDS swizzle: same XOR-chunk scheme (measured 0 bank conflicts): staging
// lane (sr=L>>3, sc=L&7) fetches global chunk gc=sc^sr, so LDS[row][pos]
// holds global chunk pos^(row&7); reads use p = c ^ (L&7).
// ---------------------------------------------------------------------------
#define BM 128
#define BN 256
#define BK 64
#define NBUF 3

#define LGKM0_FENCE() do { \
    asm volatile("s_waitcnt lgkmcnt(0)" ::: "memory"); \
    __builtin_amdgcn_sched_barrier(0); \
} while (0)

__global__ __launch_bounds__(512, 2) void gemm_bf16_bt(
    const short* __restrict__ A, const short* __restrict__ Bt,
    const float* __restrict__ bias, float* __restrict__ C,
    int M, int N, int K)
{
    __shared__ __align__(16) short a_lds[NBUF][BM * BK];   // 3 x 16 KB
    __shared__ __align__(16) short b_lds[NBUF][BN * BK];   // 3 x 32 KB

    const int t = threadIdx.x;
    const int L = t & 63;
    const int w = t >> 6;            // 0..7

    // XCD swizzle (bijective: nwg = 256, nbn = 16 divisible by 8): XCD k owns
    // n-tiles [2k, 2k+2) x all m-tiles -> B strip resident per XCD L2,
    // A streams with in-XCD reuse. Performance-only (G16-safe).
    const int nbn = N / BN;
    const int id  = blockIdx.x;
    int nt, mt;
    if ((nbn & 7) == 0) {
        const int xcd = id & 7;
        const int loc = id >> 3;
        const int gsz = nbn >> 3;
        nt = xcd * gsz + (loc % gsz);
        mt = loc / gsz;
    } else {
        nt = id % nbn;
        mt = id / nbn;
    }
    const int m0 = mt * BM;
    const int n0 = nt * BN;

    const int wm = (w & 1) * 64;
    const int wn = (w >> 1) * 64;

    floatx4 acc[4][4] = {};

    // staging geometry: one global_load_lds per wave covers 1KB = 8 rows of
    // 128B; A needs 2 per wave (128 rows), B needs 4 (256 rows).
    const int sr = L >> 3;
    const int sc = L & 7;
    const int gc = sc ^ sr;
    const short* ag = A  + (size_t)(m0 + w * 8 + sr) * K + gc * 8;
    const short* bg = Bt + (size_t)(n0 + w * 8 + sr) * K + gc * 8;
    const int adst = (w * 8) * BK;    // wave-uniform LDS offset (shorts)

    const int NT = K / BK;

    const int l15 = L & 15, l4 = L >> 4, l7 = L & 7;
    const int p0 = l4 ^ l7;          // kstep 0 chunk position
    const int p1 = (4 + l4) ^ l7;    // kstep 1 chunk position

#define STAGE(kt_, buf_) do { \
    const size_t ko_ = (size_t)(kt_) * BK; \
    __builtin_amdgcn_global_load_lds((gvoid_t*)(ag + ko_), \
        (lvoid_t*)(&a_lds[buf_][adst]), 16, 0, 0); \
    __builtin_amdgcn_global_load_lds((gvoid_t*)(ag + (size_t)64 * K + ko_), \
        (lvoid_t*)(&a_lds[buf_][adst + 64 * BK]), 16, 0, 0); \
    __builtin_amdgcn_global_load_lds((gvoid_t*)(bg + ko_), \
        (lvoid_t*)(&b_lds[buf_][adst]), 16, 0, 0); \
    __builtin_amdgcn_global_load_lds((gvoid_t*)(bg + (size_t)64 * K + ko_), \
        (lvoid_t*)(&b_lds[buf_][adst + 64 * BK]), 16, 0, 0); \
    __builtin_amdgcn_global_load_lds((gvoid_t*)(bg + (size_t)128 * K + ko_), \
        (lvoid_t*)(&b_lds[buf_][adst + 128 * BK]), 16, 0, 0); \
    __builtin_amdgcn_global_load_lds((gvoid_t*)(bg + (size_t)192 * K + ko_), \
        (lvoid_t*)(&b_lds[buf_][adst + 192 * BK]), 16, 0, 0); \
} while (0)

    // prologue: tiles 0,1 in flight (12 loads); vmcnt(6) -> tile 0 complete.
    STAGE(0, 0);
    STAGE(1, 1);
    asm volatile("s_waitcnt vmcnt(6)" ::: "memory");
    __builtin_amdgcn_s_barrier();

    int cur = 0;
    for (int ti = 0; ti < NT; ++ti) {
        // slot for tile ti+2 = (ti+2)%3 = (ti-1)%3: last read at tile ti-1,
        // whose reads completed before tile ti-1's close barrier.
        const int prv = (cur == 0) ? 2 : cur - 1;
        const short* ab = &a_lds[cur][0];
        const short* bb = &b_lds[cur][0];
        short8 a0[4], a1[4], b0f[4], b1f[4];

        // ---- P1: read kstep0 frags (8 ds_read_b128); stage tile ti+2;
        //          barrier; wait; 16 MFMA (k0).
        #pragma unroll
        for (int i = 0; i < 4; ++i)
            a0[i] = *(const short8*)(ab + (wm + 16 * i + l15) * BK + p0 * 8);
        #pragma unroll
        for (int j = 0; j < 4; ++j)
            b0f[j] = *(const short8*)(bb + (wn + 16 * j + l15) * BK + p0 * 8);
        if (ti + 2 < NT) {
            STAGE(ti + 2, prv);
        }
        __builtin_amdgcn_s_barrier();
        LGKM0_FENCE();
        __builtin_amdgcn_s_setprio(1);
        #pragma unroll
        for (int i = 0; i < 4; ++i) {
            #pragma unroll
            for (int j = 0; j < 4; ++j)
                acc[i][j] = __builtin_amdgcn_mfma_f32_16x16x32_bf16(
                    a0[i], b0f[j], acc[i][j], 0, 0, 0);
        }
        __builtin_amdgcn_s_setprio(0);
        __builtin_amdgcn_s_barrier();

        // ---- P2: read kstep1 frags (8 ds_read_b128); barrier; wait;
        //          16 MFMA (k1); counted vmcnt; close barrier.
        #pragma unroll
        for (int i = 0; i < 4; ++i)
            a1[i] = *(const short8*)(ab + (wm + 16 * i + l15) * BK + p1 * 8);
        #pragma unroll
        for (int j = 0; j < 4; ++j)
            b1f[j] = *(const short8*)(bb + (wn + 16 * j + l15) * BK + p1 * 8);
        __builtin_amdgcn_s_barrier();
        LGKM0_FENCE();
        __builtin_amdgcn_s_setprio(1);
        #pragma unroll
        for (int i = 0; i < 4; ++i) {
            #pragma unroll
            for (int j = 0; j < 4; ++j)
                acc[i][j] = __builtin_amdgcn_mfma_f32_16x16x32_bf16(
                    a1[i], b1f[j], acc[i][j], 0, 0, 0);
        }
        __builtin_amdgcn_s_setprio(0);
        if (ti + 2 < NT) {
            // outstanding = tile ti+1 (6) + tile ti+2 (6); retire ti+1's.
            asm volatile("s_waitcnt vmcnt(6)" ::: "memory");
        } else if (ti + 1 < NT) {
            // tail: only tile ti+1's loads remain -> full drain once.
            asm volatile("s_waitcnt vmcnt(0)" ::: "memory");
        }
        __builtin_amdgcn_s_barrier();

        cur = (cur == 2) ? 0 : cur + 1;
    }

    // Epilogue: C/D layout col = lane&15, row = (lane>>4)*4 + reg  (m89/m91)
    float bv[4];
    #pragma unroll
    for (int j = 0; j < 4; ++j)
        bv[j] = bias[n0 + wn + 16 * j + l15];
    const int col0 = n0 + wn + l15;
    #pragma unroll
    for (int i = 0; i < 4; ++i) {
        const int row0 = m0 + wm + 16 * i + l4 * 4;
        #pragma unroll
        for (int r = 0; r < 4; ++r) {
            float* outr = C + (size_t)(row0 + r) * N + col0;
            #pragma unroll
            for (int j = 0; j < 4; ++j)
                outr[16 * j] = acc[i][j][r] + bv[j];
        }
    }
}

// ---------------------------------------------------------------------------
extern "C" void kernel_launch(void* const* d_in, const int* in_sizes, int n_in,
                              void* d_out, int out_size, void* d_ws, size_t ws_size,
                              hipStream_t stream)
{
    const float* x      = (const float*)d_in[0];
    const float* scales = (const float*)d_in[1];
    const float* zps    = (const float*)d_in[2];
    const float* bias   = (const float*)d_in[3];
    const int*   qw     = (const int*)d_in[4];

    const int N = in_sizes[3];          // outfeatures (bias length)
    const int G = in_sizes[1] / N;      // num groups
    const int K = G * 128;              // infeatures
    const int M = in_sizes[0] / K;      // tokens

    short* xb   = (short*)d_ws;                       // M*K bf16
    short* deqT = xb + (size_t)M * K;                 // N*K bf16
    float* out  = (float*)d_out;

    const long long nx = (long long)M * K;
    const int ncvt = (int)(nx / 2048);
    const int nbx  = N / 64;
    const int ndq  = nbx * (K / 256);

    prologue_kernel<<<ncvt + ndq, 256, 0, stream>>>(
        x, xb, nx, ncvt, qw, scales, zps, deqT, N, K, nbx);
    gemm_bf16_bt<<<dim3((M / BM) * (N / BN)), 512, 0, stream>>>(
        xb, deqT, bias, out, M, N, K);
}